// Round 1
// baseline (28.684 us; speedup 1.0000x reference)
//
#include <hip/hip_runtime.h>
#include <hip/hip_bf16.h>

#define DIM 4096      // 2^12
#define NW  12
#define BATCH 64
#define BLK 256

// One workgroup per batch column. Stage the 4096-element complex column in
// LDS (fp32 re/im), apply the 12 RX butterflies in place, write out.
__global__ __launch_bounds__(BLK)
void rx_apply_kernel(const float* __restrict__ theta,
                     const float* __restrict__ xr,
                     const float* __restrict__ xi,
                     float* __restrict__ out) {
    __shared__ float sr[DIM];
    __shared__ float si[DIM];

    const int b   = blockIdx.x;   // batch column
    const int tid = threadIdx.x;

    // Load column b: element (d, b) at d*BATCH + b
    #pragma unroll
    for (int j = tid; j < DIM; j += BLK) {
        sr[j] = xr[j * BATCH + b];
        si[j] = xi[j * BATCH + b];
    }
    __syncthreads();

    // Wire w acts on bit position (NW-1-w): first kron factor = MSB.
    for (int w = 0; w < NW; ++w) {
        const int   k    = NW - 1 - w;
        const float t    = theta[w];
        const float c    = cosf(t);
        const float s    = sinf(t);
        const int   bit  = 1 << k;
        const int   mask = bit - 1;

        #pragma unroll
        for (int p = tid; p < DIM / 2; p += BLK) {
            const int i0 = ((p & ~mask) << 1) | (p & mask);
            const int i1 = i0 | bit;

            const float r0 = sr[i0], m0 = si[i0];
            const float r1 = sr[i1], m1 = si[i1];

            // [[c, -i s], [-i s, c]] applied to (a0, a1)
            sr[i0] = c * r0 + s * m1;
            si[i0] = c * m0 - s * r1;
            sr[i1] = c * r1 + s * m0;
            si[i1] = c * m1 - s * r0;
        }
        __syncthreads();
    }

    // Store: out[0] = real [DIM][BATCH], out[1] = imag [DIM][BATCH]
    #pragma unroll
    for (int j = tid; j < DIM; j += BLK) {
        out[j * BATCH + b]              = sr[j];
        out[DIM * BATCH + j * BATCH + b] = si[j];
    }
}

extern "C" void kernel_launch(void* const* d_in, const int* in_sizes, int n_in,
                              void* d_out, int out_size, void* d_ws, size_t ws_size,
                              hipStream_t stream) {
    const float* theta = (const float*)d_in[0];  // [12,1]
    const float* xr    = (const float*)d_in[1];  // [4096,64]
    const float* xi    = (const float*)d_in[2];  // [4096,64]
    float*       out   = (float*)d_out;          // [2,4096,64]

    rx_apply_kernel<<<BATCH, BLK, 0, stream>>>(theta, xr, xi, out);
}

// Round 2
// 19.990 us; speedup vs baseline: 1.4349x; 1.4349x over previous
//
#include <hip/hip_runtime.h>
#include <hip/hip_bf16.h>

#define DIM   4096   // 2^12
#define NW    12
#define BATCH 64     // == wavefront size: lane = batch column

// Butterfly for RX gate [[c, -i s], [-i s, c]] applied to complex pair (a0, a1):
//   new_r0 = c*r0 + s*i1     new_i0 = c*i0 - s*r1
//   new_r1 = c*r1 + s*i0     new_i1 = c*i1 - s*r0
// Wire w acts on row-index bit (11 - w)  (first kron factor is the MSB).

// Kernel 1: bits 0..5 (wires 11..6). Block g owns contiguous rows [g*64, g*64+64).
// One wave; lane = batch col; 64 rows live in VGPRs.
__global__ __launch_bounds__(64)
void rx_low(const float* __restrict__ theta,
            const float* __restrict__ xr,
            const float* __restrict__ xi,
            float* __restrict__ out) {
    const int g    = blockIdx.x;
    const int lane = threadIdx.x;
    const int base = g * 64;

    float vr[64], vi[64];
    #pragma unroll
    for (int lo = 0; lo < 64; ++lo) {
        vr[lo] = xr[(base + lo) * BATCH + lane];
        vi[lo] = xi[(base + lo) * BATCH + lane];
    }

    #pragma unroll
    for (int k = 0; k < 6; ++k) {
        const float t = theta[11 - k];        // wire = 11 - bit
        const float c = cosf(t);
        const float s = sinf(t);
        const int bit = 1 << k, mask = bit - 1;
        #pragma unroll
        for (int p = 0; p < 32; ++p) {
            const int i0 = ((p & ~mask) << 1) | (p & mask);
            const int i1 = i0 | bit;
            const float r0 = vr[i0], m0 = vi[i0];
            const float r1 = vr[i1], m1 = vi[i1];
            vr[i0] = fmaf(c, r0,  s * m1);
            vi[i0] = fmaf(c, m0, -s * r1);
            vr[i1] = fmaf(c, r1,  s * m0);
            vi[i1] = fmaf(c, m1, -s * r0);
        }
    }

    float* __restrict__ outr = out;
    float* __restrict__ outi = out + DIM * BATCH;
    #pragma unroll
    for (int lo = 0; lo < 64; ++lo) {
        outr[(base + lo) * BATCH + lane] = vr[lo];
        outi[(base + lo) * BATCH + lane] = vi[lo];
    }
}

// Kernel 2: bits 6..11 (wires 5..0). Block g owns rows {hi*64 + g}, hi in [0,64).
// Reads/writes d_out in place; each block's row slice is exclusive.
__global__ __launch_bounds__(64)
void rx_high(const float* __restrict__ theta,
             float* __restrict__ out) {
    const int g    = blockIdx.x;
    const int lane = threadIdx.x;

    float* __restrict__ outr = out;
    float* __restrict__ outi = out + DIM * BATCH;

    float vr[64], vi[64];
    #pragma unroll
    for (int hi = 0; hi < 64; ++hi) {
        vr[hi] = outr[(hi * 64 + g) * BATCH + lane];
        vi[hi] = outi[(hi * 64 + g) * BATCH + lane];
    }

    #pragma unroll
    for (int j = 0; j < 6; ++j) {            // local bit j over hi == global bit 6+j
        const float t = theta[5 - j];        // wire = 11 - (6+j) = 5 - j
        const float c = cosf(t);
        const float s = sinf(t);
        const int bit = 1 << j, mask = bit - 1;
        #pragma unroll
        for (int p = 0; p < 32; ++p) {
            const int i0 = ((p & ~mask) << 1) | (p & mask);
            const int i1 = i0 | bit;
            const float r0 = vr[i0], m0 = vi[i0];
            const float r1 = vr[i1], m1 = vi[i1];
            vr[i0] = fmaf(c, r0,  s * m1);
            vi[i0] = fmaf(c, m0, -s * r1);
            vr[i1] = fmaf(c, r1,  s * m0);
            vi[i1] = fmaf(c, m1, -s * r0);
        }
    }

    #pragma unroll
    for (int hi = 0; hi < 64; ++hi) {
        outr[(hi * 64 + g) * BATCH + lane] = vr[hi];
        outi[(hi * 64 + g) * BATCH + lane] = vi[hi];
    }
}

extern "C" void kernel_launch(void* const* d_in, const int* in_sizes, int n_in,
                              void* d_out, int out_size, void* d_ws, size_t ws_size,
                              hipStream_t stream) {
    const float* theta = (const float*)d_in[0];  // [12,1]
    const float* xr    = (const float*)d_in[1];  // [4096,64]
    const float* xi    = (const float*)d_in[2];  // [4096,64]
    float*       out   = (float*)d_out;          // [2,4096,64]

    rx_low <<<64, 64, 0, stream>>>(theta, xr, xi, out);
    rx_high<<<64, 64, 0, stream>>>(theta, out);
}